// Round 4
// baseline (317.697 us; speedup 1.0000x reference)
//
#include <hip/hip_runtime.h>
#include <hip/hip_bf16.h>
#include <math.h>

#define NN 4096      // nodes
#define NE 16384     // edges
#define FIN 64
#define FE 16
#define HIDD 128
#define OUTD 64
#define NG 32
#define EP (NE + NN) // edges + self loops
#define KSPLIT 2
#define NCH (64 / KSPLIT)  // 32 chunks per block

typedef __attribute__((ext_vector_type(8))) short s8v;
typedef __attribute__((ext_vector_type(4))) unsigned u4v;
typedef __attribute__((ext_vector_type(4))) float f4v;

union FragU { u4v u; s8v s; };

__device__ __forceinline__ unsigned bf16_rne(float v) {
    unsigned b = __float_as_uint(v);
    return (b + 0x7FFFu + ((b >> 16) & 1u)) >> 16;
}

__device__ __forceinline__ void glds16(const void* g, void* l) {
    __builtin_amdgcn_global_load_lds(
        (const __attribute__((address_space(1))) unsigned*)g,
        (__attribute__((address_space(3))) unsigned*)l, 16, 0, 0);
}

// ================= prep: splitB | edge MLP | bias | dst-hist | batch-hist =========
#define PB_SPLIT 2048
#define PB_EMLP  (PB_SPLIT + 4096)
#define PB_BIAS  (PB_EMLP + 4096)
#define PB_HIST  (PB_BIAS + 32)
#define PB_TOTAL (PB_HIST + 2)

__global__ void k_prep(const float* __restrict__ ea0, const float* __restrict__ ea1,
                       const float* __restrict__ w1, const float* __restrict__ b1,
                       const float* __restrict__ w2, const float* __restrict__ b2,
                       const float* __restrict__ w3,
                       const float* __restrict__ X0, const float* __restrict__ X1,
                       const float* __restrict__ b3,
                       const int* __restrict__ ei0, const int* __restrict__ ei1,
                       const int* __restrict__ batch0, const int* __restrict__ batch1,
                       unsigned short* __restrict__ B1g, unsigned short* __restrict__ B2g,
                       float* __restrict__ h0, float* __restrict__ h1g,
                       float* __restrict__ Bb0, float* __restrict__ Bb1,
                       int* __restrict__ rowcnt, int* __restrict__ bcnt) {
    int b = blockIdx.x, t = threadIdx.x; // 256
    if (b < PB_SPLIT) {
        int g = b * 256 + t;
        int o = g & 127, i = (g >> 7) & 63, c = g >> 13;
        float v = w3[(size_t)c * 8192 + i * 128 + o];
        unsigned hi = __float_as_uint(v) & 0xFFFF0000u;
        float res = v - __uint_as_float(hi);
        unsigned r2 = bf16_rne(res);
        unsigned idx = ((unsigned)c << 13) + (((o << 6) + i) ^ ((o & 7) << 3));
        B1g[idx] = (unsigned short)(hi >> 16);
        B2g[idx] = (unsigned short)r2;
    } else if (b < PB_EMLP) {
        int bb = b - PB_SPLIT;        // 0..4095
        int gi = bb >> 11;
        int e0 = (bb & 2047) * 8;
        const float* ea = gi ? ea1 : ea0;
        float* hout = gi ? h1g : h0;
        __shared__ float h1s[8][HIDD];
#pragma unroll
        for (int r = 0; r < 4; ++r) {
            int idx = r * 256 + t;
            int e1 = idx >> 7, j = idx & 127;
            float acc = b1[j];
#pragma unroll
            for (int i = 0; i < FE; ++i) acc += ea[(e0 + e1) * FE + i] * w1[i * HIDD + j];
            h1s[e1][j] = fmaxf(acc, 0.f);
        }
        __syncthreads();
#pragma unroll
        for (int r = 0; r < 2; ++r) {
            int idx = r * 256 + t;
            int e1 = idx >> 6, j = idx & 63;
            float acc = b2[j];
#pragma unroll 16
            for (int k = 0; k < HIDD; ++k) acc += h1s[e1][k] * w2[k * 64 + j];
            hout[(size_t)(e0 + e1) * 64 + j] = fmaxf(acc, 0.f);
        }
    } else if (b < PB_BIAS) {
        int bb = b - PB_EMLP;         // 0..4095
        int gi = bb >> 11;
        int n = (bb & 2047) * 2 + (t >> 7);
        int o = t & 127;
        const float* X = gi ? X1 : X0;
        float* Bb = gi ? Bb1 : Bb0;
        float acc = 0.f;
#pragma unroll 16
        for (int i = 0; i < FIN; ++i) acc += X[n * FIN + i] * b3[i * HIDD + o];
        Bb[(size_t)n * HIDD + o] = acc;
    } else if (b < PB_HIST) {
        int tid = (b - PB_BIAS) * 256 + t; // 0..8191
        for (int idx = tid; idx < 2 * EP; idx += 32 * 256) {
            int gi = idx / EP, e = idx % EP;
            const int* dst = (gi ? ei1 : ei0) + NE;
            int d = (e < NE) ? dst[e] : e - NE;
            atomicAdd(&rowcnt[gi * NN + d], 1);
        }
    } else {
        int gi = b - PB_HIST; // 0,1
        const int* batch = gi ? batch1 : batch0;
        for (int n = t; n < NN; n += 256) atomicAdd(&bcnt[gi * 32 + batch[n]], 1);
    }
}

// ================= scan: rowptr per graph + batch ranges =================
__global__ void k_scan(const int* __restrict__ rowcnt, int* __restrict__ rowptr,
                       const int* __restrict__ bcnt, int* __restrict__ br) {
    int b = blockIdx.x;
    if (b < 2) {
        int gi = b;
        const int* cnt = rowcnt + gi * NN;
        int* rp = rowptr + gi * (NN + 1);
        int t = threadIdx.x; // 1024
        int base = t * 4;
        int v0 = cnt[base], v1 = cnt[base + 1], v2 = cnt[base + 2], v3 = cnt[base + 3];
        int s = v0 + v1 + v2 + v3;
        __shared__ int sc[1024];
        sc[t] = s;
        __syncthreads();
        for (int off = 1; off < 1024; off <<= 1) {
            int a = (t >= off) ? sc[t - off] : 0;
            __syncthreads();
            sc[t] += a;
            __syncthreads();
        }
        int run = sc[t] - s; // exclusive
        rp[base] = run; run += v0;
        rp[base + 1] = run; run += v1;
        rp[base + 2] = run; run += v2;
        rp[base + 3] = run; run += v3;
        if (t == 1023) rp[NN] = run;
    } else {
        int t = threadIdx.x;
        if (t < 2) {
            int gi = t;
            int run = 0;
            for (int g = 0; g < 32; ++g) { br[gi * 33 + g] = run; run += bcnt[gi * 32 + g]; }
            br[gi * 33 + 32] = run;
        }
    }
}

// ================= fill CSR adjacency =================
__global__ void k_fill(const int* __restrict__ ei0, const int* __restrict__ ei1,
                       const int* __restrict__ rowptr, int* __restrict__ cnt2,
                       int* __restrict__ adj) {
    int idx = blockIdx.x * 256 + threadIdx.x;
    if (idx >= 2 * EP) return;
    int gi = idx / EP, e = idx % EP;
    const int* dst = (gi ? ei1 : ei0) + NE;
    int d = (e < NE) ? dst[e] : e - NE;
    int pos = rowptr[gi * (NN + 1) + d] + atomicAdd(&cnt2[gi * NN + d], 1);
    adj[gi * EP + pos] = e;
}

// ================= NNConv message GEMM -> msg[g][z][e][o] (no atomics) ========
__global__ void __launch_bounds__(256, 2)
k_nnconv(const float* __restrict__ x0, const float* __restrict__ x1,
         const float* __restrict__ h_0, const float* __restrict__ h_1,
         const unsigned short* __restrict__ B1g, const unsigned short* __restrict__ B2g,
         const float* __restrict__ Bb0, const float* __restrict__ Bb1,
         const int* __restrict__ ei0, const int* __restrict__ ei1,
         float* __restrict__ msg) {
    __shared__ __align__(16) char smem[65536]; // 2 bufs x (B1 16K | B2 16K)
    int gi = blockIdx.z;
    const float* x = gi ? x1 : x0;
    const float* hh = gi ? h_1 : h_0;
    const float* Bb = gi ? Bb1 : Bb0;
    const int* src = gi ? ei1 : ei0;

    int t = threadIdx.x;          // 256
    int e0 = blockIdx.x * 128;
    int z = blockIdx.y;           // 0..KSPLIT-1
    int wv = t >> 6, l = t & 63;
    int q4 = l >> 4, c16 = l & 15;

    // prologue: x slices + h slices for this wave's 2 row-tiles, in registers
    float xs[2][16];  // [mf][kf*8+e]: x[src[row]][kf*32 + q4*8 + e]
    float hs[2][NCH]; // [mf][cl]:     h[row][z*NCH + cl]
#pragma unroll
    for (int mf = 0; mf < 2; ++mf) {
        int r = wv * 32 + mf * 16 + c16;
        int s_ = src[e0 + r];
        const float* xr = &x[(size_t)s_ * FIN];
        *(float4*)&xs[mf][0]  = *(const float4*)&xr[q4 * 8];
        *(float4*)&xs[mf][4]  = *(const float4*)&xr[q4 * 8 + 4];
        *(float4*)&xs[mf][8]  = *(const float4*)&xr[32 + q4 * 8];
        *(float4*)&xs[mf][12] = *(const float4*)&xr[32 + q4 * 8 + 4];
        const float* hr = &hh[(size_t)(e0 + r) * 64 + z * NCH];
#pragma unroll
        for (int q = 0; q < NCH / 4; ++q)
            *(float4*)&hs[mf][q * 4] = *(const float4*)&hr[q * 4];
    }

    f4v acc[2][8];
#pragma unroll
    for (int a = 0; a < 2; ++a)
#pragma unroll
        for (int b = 0; b < 8; ++b) acc[a][b] = (f4v){0.f, 0.f, 0.f, 0.f};

    int woff = wv << 10;
#define STAGE(cg, buf)                                                         \
    {                                                                          \
        const char* b1src = (const char*)B1g + (size_t)(cg) * 16384;           \
        const char* b2src = (const char*)B2g + (size_t)(cg) * 16384;           \
        char* B1s_ = smem + (buf) * 32768;                                     \
        char* B2s_ = B1s_ + 16384;                                             \
        _Pragma("unroll")                                                      \
        for (int k2 = 0; k2 < 4; ++k2) {                                       \
            glds16(b1src + k2 * 4096 + t * 16, B1s_ + k2 * 4096 + woff);       \
            glds16(b2src + k2 * 4096 + t * 16, B2s_ + k2 * 4096 + woff);       \
        }                                                                      \
    }

    STAGE(z * NCH, 0);

#pragma unroll 1
    for (int cl = 0; cl < NCH; ++cl) {
        int buf = cl & 1;
        __builtin_amdgcn_s_barrier();          // WAR: all waves done reading buf^1
        __builtin_amdgcn_sched_barrier(0);
        if (cl + 1 < NCH) STAGE(z * NCH + cl + 1, buf ^ 1);

        // synthesize A fragments in registers (overlaps the staging loads)
        FragU a1[2][2], a2[2][2]; // [mf][kf]
#pragma unroll
        for (int mf = 0; mf < 2; ++mf) {
            float hv = hs[mf][cl];
#pragma unroll
            for (int kf = 0; kf < 2; ++kf) {
                u4v w1v, w2v;
#pragma unroll
                for (int p = 0; p < 4; ++p) {
                    float p0 = hv * xs[mf][kf * 8 + 2 * p];
                    float p1 = hv * xs[mf][kf * 8 + 2 * p + 1];
                    unsigned b0 = __float_as_uint(p0), b1 = __float_as_uint(p1);
                    unsigned hi0 = b0 & 0xFFFF0000u, hi1 = b1 & 0xFFFF0000u;
                    w1v[p] = (hi0 >> 16) | hi1;
                    float r0 = p0 - __uint_as_float(hi0);
                    float r1 = p1 - __uint_as_float(hi1);
                    w2v[p] = bf16_rne(r0) | (bf16_rne(r1) << 16);
                }
                a1[mf][kf].u = w1v; a2[mf][kf].u = w2v;
            }
        }

        if (cl + 1 < NCH) { asm volatile("s_waitcnt vmcnt(8)" ::: "memory"); }
        else             { asm volatile("s_waitcnt vmcnt(0)" ::: "memory"); }
        __builtin_amdgcn_sched_barrier(0);
        __builtin_amdgcn_s_barrier();          // buf fully staged for all waves
        __builtin_amdgcn_sched_barrier(0);

        const char* B1s = smem + buf * 32768;
        const char* B2s = B1s + 16384;
        __builtin_amdgcn_s_setprio(1);
#pragma unroll
        for (int kf = 0; kf < 2; ++kf) {
#pragma unroll
            for (int nf = 0; nf < 8; ++nf) {
                int o = nf * 16 + c16;
                int byte = o * 128 + ((kf * 64 + q4 * 16) ^ ((o & 7) << 4));
                FragU bf1, bf2;
                bf1.u = *(const u4v*)(B1s + byte);
                bf2.u = *(const u4v*)(B2s + byte);
#pragma unroll
                for (int mf = 0; mf < 2; ++mf) {
                    acc[mf][nf] = __builtin_amdgcn_mfma_f32_16x16x32_bf16(a1[mf][kf].s, bf1.s, acc[mf][nf], 0, 0, 0);
                    acc[mf][nf] = __builtin_amdgcn_mfma_f32_16x16x32_bf16(a1[mf][kf].s, bf2.s, acc[mf][nf], 0, 0, 0);
                    acc[mf][nf] = __builtin_amdgcn_mfma_f32_16x16x32_bf16(a2[mf][kf].s, bf1.s, acc[mf][nf], 0, 0, 0);
                }
            }
        }
        __builtin_amdgcn_s_setprio(0);
    }
#undef STAGE

    // epilogue: coalesced store to msg[gi][z][e][o]; add Bb[src] once (z==0)
    float* mb = msg + ((size_t)(gi * KSPLIT + z) * NE) * HIDD;
    int z0 = (z == 0);
#pragma unroll
    for (int mf = 0; mf < 2; ++mf) {
#pragma unroll
        for (int j = 0; j < 4; ++j) {
            int r = wv * 32 + mf * 16 + q4 * 4 + j;
            int eg = e0 + r;
            int s_ = src[eg];
            const float* bbr = &Bb[(size_t)s_ * HIDD];
            float* mrow = mb + (size_t)eg * HIDD;
#pragma unroll
            for (int nf = 0; nf < 8; ++nf) {
                int o = nf * 16 + c16;
                float v = acc[mf][nf][j];
                if (z0) v += bbr[o];
                mrow[o] = v;
            }
        }
    }
}

// ===== h1 = relu(gather(msg) + x@root_w + cb); hp = h1@gat_w; a_s,a_d =====
__global__ void k_h1hp(const float* __restrict__ msg,
                       const int* __restrict__ rowptr, const int* __restrict__ adj,
                       const float* __restrict__ X0, const float* __restrict__ X1,
                       const float* __restrict__ rw, const float* __restrict__ cb,
                       const float* __restrict__ gw,
                       const float* __restrict__ asw, const float* __restrict__ adw,
                       float* __restrict__ hp0, float* __restrict__ hp1,
                       float* __restrict__ a_s0, float* __restrict__ a_s1,
                       float* __restrict__ a_d0, float* __restrict__ a_d1) {
    int gi = blockIdx.y;
    const float* X = gi ? X1 : X0;
    float* hp = gi ? hp1 : hp0;
    float* a_s = gi ? a_s1 : a_s0;
    float* a_d = gi ? a_d1 : a_d0;
    const int* rp = rowptr + gi * (NN + 1);
    const int* aj = adj + gi * EP;
    const float* mz0 = msg + (size_t)(gi * KSPLIT + 0) * NE * HIDD;
    const float* mz1 = msg + (size_t)(gi * KSPLIT + 1) * NE * HIDD;
    int n0 = blockIdx.x * 4;
    int o = threadIdx.x; // 128
    __shared__ float xsh[4][FIN];
    __shared__ float h1s[4][HIDD];
    __shared__ float s1[4][2], s2[4][2];
    xsh[o >> 6][o & 63] = X[n0 * FIN + o];
    xsh[2 + (o >> 6)][o & 63] = X[n0 * FIN + 128 + o];
    __syncthreads();
    float accs[4];
#pragma unroll
    for (int nn = 0; nn < 4; ++nn) {
        int n = n0 + nn;
        float acc = cb[o];
        int lo = rp[n], hi = rp[n + 1];
        for (int p = lo; p < hi; ++p) {
            int e = aj[p];
            if (e < NE) acc += mz0[(size_t)e * HIDD + o] + mz1[(size_t)e * HIDD + o];
        }
        accs[nn] = acc;
    }
#pragma unroll 8
    for (int i = 0; i < FIN; ++i) {
        float w = rw[i * HIDD + o];
#pragma unroll
        for (int nn = 0; nn < 4; ++nn) accs[nn] += xsh[nn][i] * w;
    }
#pragma unroll
    for (int nn = 0; nn < 4; ++nn) h1s[nn][o] = fmaxf(accs[nn], 0.f);
    __syncthreads();
#pragma unroll
    for (int nn = 0; nn < 4; ++nn) accs[nn] = 0.f;
#pragma unroll 8
    for (int k = 0; k < HIDD; ++k) {
        float w = gw[k * HIDD + o];
#pragma unroll
        for (int nn = 0; nn < 4; ++nn) accs[nn] += h1s[nn][k] * w;
    }
#pragma unroll
    for (int nn = 0; nn < 4; ++nn) {
        hp[(size_t)(n0 + nn) * HIDD + o] = accs[nn];
        float p1 = accs[nn] * asw[o], p2 = accs[nn] * adw[o];
#pragma unroll
        for (int off = 32; off; off >>= 1) {
            p1 += __shfl_down(p1, off);
            p2 += __shfl_down(p2, off);
        }
        if ((o & 63) == 0) { s1[nn][o >> 6] = p1; s2[nn][o >> 6] = p2; }
    }
    __syncthreads();
    if (o < 4) {
        a_s[n0 + o] = s1[o][0] + s1[o][1];
        a_d[n0 + o] = s2[o][0] + s2[o][1];
    }
}

// ===== GAT: wave per dst node; local max/denom/weighted-sum; h2 = relu(.+gb) =====
__global__ void k_gat(const int* __restrict__ rowptr, const int* __restrict__ adj,
                      const int* __restrict__ ei0, const int* __restrict__ ei1,
                      const float* __restrict__ hp0, const float* __restrict__ hp1,
                      const float* __restrict__ as0, const float* __restrict__ as1,
                      const float* __restrict__ ad0, const float* __restrict__ ad1,
                      const float* __restrict__ gb,
                      float* __restrict__ h2_0, float* __restrict__ h2_1) {
    int gi = blockIdx.y;
    const int* src = gi ? ei1 : ei0;
    const float* hp = gi ? hp1 : hp0;
    const float* a_s = gi ? as1 : as0;
    const float* a_d = gi ? ad1 : ad0;
    float* h2 = gi ? h2_1 : h2_0;
    const int* rp = rowptr + gi * (NN + 1);
    const int* aj = adj + gi * EP;
    int w = threadIdx.x >> 6, l = threadIdx.x & 63;
    int n = blockIdx.x * 4 + w;
    int lo = rp[n], deg = rp[n + 1] - lo;
    float adn = a_d[n];
    float m = -1e30f;
    for (int base = 0; base < deg; base += 64) {
        float sc = -1e30f;
        int j = base + l;
        if (j < deg) {
            int e = aj[lo + j];
            int si = (e < NE) ? src[e] : n;
            float xsc = a_s[si] + adn;
            sc = xsc > 0.f ? xsc : 0.2f * xsc;
        }
#pragma unroll
        for (int off = 32; off; off >>= 1) sc = fmaxf(sc, __shfl_xor(sc, off));
        m = fmaxf(m, sc);
    }
    float den = 0.f;
    for (int base = 0; base < deg; base += 64) {
        float ev = 0.f;
        int j = base + l;
        if (j < deg) {
            int e = aj[lo + j];
            int si = (e < NE) ? src[e] : n;
            float xsc = a_s[si] + adn;
            float sc = xsc > 0.f ? xsc : 0.2f * xsc;
            ev = expf(sc - m);
        }
#pragma unroll
        for (int off = 32; off; off >>= 1) ev += __shfl_xor(ev, off);
        den += ev;
    }
    float inv = 1.f / (den + 1e-16f);
    float acc0 = 0.f, acc1 = 0.f;
    for (int j = 0; j < deg; ++j) {
        int e = aj[lo + j];
        int si = (e < NE) ? src[e] : n;
        float xsc = a_s[si] + adn;
        float sc = xsc > 0.f ? xsc : 0.2f * xsc;
        float al = expf(sc - m) * inv;
        acc0 += al * hp[(size_t)si * HIDD + l];
        acc1 += al * hp[(size_t)si * HIDD + 64 + l];
    }
    h2[(size_t)n * HIDD + l] = fmaxf(acc0 + gb[l], 0.f);
    h2[(size_t)n * HIDD + 64 + l] = fmaxf(acc1 + gb[64 + l], 0.f);
}

// ===== mean-pool (batch ranges) + fc1, no atomics =====
__global__ void k_poolfc1(const float* __restrict__ h2_0, const float* __restrict__ h2_1,
                          const int* __restrict__ br,
                          const float* __restrict__ w, const float* __restrict__ bias,
                          float* __restrict__ z) {
    int gi = blockIdx.x >> 5, g = blockIdx.x & 31;
    const float* h2 = gi ? h2_1 : h2_0;
    int lo = br[gi * 33 + g], hi = br[gi * 33 + g + 1];
    int t = threadIdx.x; // 128
    __shared__ float pool[HIDD];
    float acc = 0.f;
    for (int n = lo; n < hi; ++n) acc += h2[(size_t)n * HIDD + t];
    pool[t] = acc;
    __syncthreads();
    if (t < 64) {
        float c = fmaxf((float)(hi - lo), 1.f);
        float a = bias[t];
#pragma unroll 16
        for (int o = 0; o < HIDD; ++o) a += (pool[o] / c) * w[o * OUTD + t];
        z[gi * NG * OUTD + g * OUTD + t] = fmaxf(a, 0.f);
    }
}

// ===== final =====
__global__ void k_final(const float* __restrict__ zz,
                        const float* __restrict__ w, const float* __restrict__ b,
                        float* __restrict__ out) {
    int g = threadIdx.x; // 32
    const float* z1 = zz;
    const float* z2 = zz + NG * OUTD;
    float acc = b[0];
#pragma unroll
    for (int j = 0; j < OUTD; ++j) acc += fabsf(z1[g * OUTD + j] - z2[g * OUTD + j]) * w[j];
    out[g] = 1.f / (1.f + expf(-acc));
}

extern "C" void kernel_launch(void* const* d_in, const int* in_sizes, int n_in,
                              void* d_out, int out_size, void* d_ws, size_t ws_size,
                              hipStream_t stream) {
    const float* x0     = (const float*)d_in[0];
    const int*   ei0    = (const int*)d_in[1];
    const float* ea0    = (const float*)d_in[2];
    const int*   b0     = (const int*)d_in[3];
    const float* x1     = (const float*)d_in[4];
    const int*   ei1    = (const int*)d_in[5];
    const float* ea1    = (const float*)d_in[6];
    const int*   b1     = (const int*)d_in[7];
    const float* e_w1 = (const float*)d_in[8];
    const float* e_b1 = (const float*)d_in[9];
    const float* e_w2 = (const float*)d_in[10];
    const float* e_b2 = (const float*)d_in[11];
    const float* e_w3 = (const float*)d_in[12];
    const float* e_b3 = (const float*)d_in[13];
    const float* root_w = (const float*)d_in[14];
    const float* conv1_b = (const float*)d_in[15];
    const float* gat_w = (const float*)d_in[16];
    const float* att_src = (const float*)d_in[17];
    const float* att_dst = (const float*)d_in[18];
    const float* gat_b = (const float*)d_in[19];
    const float* fc1_w = (const float*)d_in[20];
    const float* fc1_b = (const float*)d_in[21];
    const float* fc2_w = (const float*)d_in[22];
    const float* fc2_b = (const float*)d_in[23];

    float* ws = (float*)d_ws;
    size_t off = 0;
    auto alloc = [&](size_t n) { float* p = ws + off; off += n; return p; };
    // int region (zeroed part first)
    int* rowcnt = (int*)alloc(2 * NN);
    int* cnt2   = (int*)alloc(2 * NN);
    int* bcnt   = (int*)alloc(64);
    size_t zero_elems = off;
    int* rowptr = (int*)alloc(2 * (NN + 1));
    int* br     = (int*)alloc(66);
    int* adj    = (int*)alloc(2 * EP);
    // float scratch
    float* h[2]   = {alloc((size_t)NE * 64), alloc((size_t)NE * 64)};
    unsigned short* B1g = (unsigned short*)alloc((size_t)4096 * 128 / 2);
    unsigned short* B2g = (unsigned short*)alloc((size_t)4096 * 128 / 2);
    float* Bb[2]  = {alloc((size_t)NN * HIDD), alloc((size_t)NN * HIDD)};
    float* msg    = alloc((size_t)2 * KSPLIT * NE * HIDD);   // [g][z][e][o]
    float* hp[2]  = {alloc((size_t)NN * HIDD), alloc((size_t)NN * HIDD)};
    float* a_s[2] = {alloc(NN), alloc(NN)};
    float* a_d[2] = {alloc(NN), alloc(NN)};
    float* h2[2]  = {alloc((size_t)NN * HIDD), alloc((size_t)NN * HIDD)};
    float* zz     = alloc((size_t)2 * NG * OUTD);

    hipMemsetAsync(ws, 0, zero_elems * 4, stream);
    k_prep<<<PB_TOTAL, 256, 0, stream>>>(ea0, ea1, e_w1, e_b1, e_w2, e_b2, e_w3,
                                         x0, x1, e_b3, ei0, ei1, b0, b1,
                                         B1g, B2g, h[0], h[1], Bb[0], Bb[1],
                                         rowcnt, bcnt);
    k_scan<<<3, 1024, 0, stream>>>(rowcnt, rowptr, bcnt, br);
    k_fill<<<(2 * EP + 255) / 256, 256, 0, stream>>>(ei0, ei1, rowptr, cnt2, adj);
    k_nnconv<<<dim3(NE / 128, KSPLIT, 2), 256, 0, stream>>>(
        x0, x1, h[0], h[1], B1g, B2g, Bb[0], Bb[1], ei0, ei1, msg);
    k_h1hp<<<dim3(NN / 4, 2), HIDD, 0, stream>>>(
        msg, rowptr, adj, x0, x1, root_w, conv1_b, gat_w, att_src, att_dst,
        hp[0], hp[1], a_s[0], a_s[1], a_d[0], a_d[1]);
    k_gat<<<dim3(NN / 4, 2), 256, 0, stream>>>(
        rowptr, adj, ei0, ei1, hp[0], hp[1], a_s[0], a_s[1], a_d[0], a_d[1],
        gat_b, h2[0], h2[1]);
    k_poolfc1<<<64, HIDD, 0, stream>>>(h2[0], h2[1], br, fc1_w, fc1_b, zz);
    k_final<<<1, NG, 0, stream>>>(zz, fc2_w, fc2_b, (float*)d_out);
}

// Round 5
// 255.063 us; speedup vs baseline: 1.2456x; 1.2456x over previous
//
#include <hip/hip_runtime.h>
#include <hip/hip_bf16.h>
#include <math.h>

#define NN 4096      // nodes
#define NE 16384     // edges
#define FIN 64
#define FE 16
#define HIDD 128
#define OUTD 64
#define NG 32
#define EP (NE + NN) // edges + self loops
#define KSPLIT 2
#define NCH (64 / KSPLIT)  // 32 chunks per block

typedef __attribute__((ext_vector_type(8))) short s8v;
typedef __attribute__((ext_vector_type(4))) unsigned u4v;
typedef __attribute__((ext_vector_type(4))) float f4v;

union FragU { u4v u; s8v s; };

__device__ __forceinline__ unsigned bf16_rne(float v) {
    unsigned b = __float_as_uint(v);
    return (b + 0x7FFFu + ((b >> 16) & 1u)) >> 16;
}

__device__ __forceinline__ void glds16(const void* g, void* l) {
    __builtin_amdgcn_global_load_lds(
        (const __attribute__((address_space(1))) unsigned*)g,
        (__attribute__((address_space(3))) unsigned*)l, 16, 0, 0);
}

// ================= prep: splitB | edge MLP | bias | dst-hist =========
#define PB_SPLIT 2048
#define PB_EMLP  (PB_SPLIT + 4096)
#define PB_BIAS  (PB_EMLP + 4096)
#define PB_TOTAL (PB_BIAS + 32)

__global__ void k_prep(const float* __restrict__ ea0, const float* __restrict__ ea1,
                       const float* __restrict__ w1, const float* __restrict__ b1,
                       const float* __restrict__ w2, const float* __restrict__ b2,
                       const float* __restrict__ w3,
                       const float* __restrict__ X0, const float* __restrict__ X1,
                       const float* __restrict__ b3,
                       const int* __restrict__ ei0, const int* __restrict__ ei1,
                       unsigned short* __restrict__ B1g, unsigned short* __restrict__ B2g,
                       float* __restrict__ h0, float* __restrict__ h1g,
                       float* __restrict__ Bb0, float* __restrict__ Bb1,
                       int* __restrict__ rowcnt) {
    int b = blockIdx.x, t = threadIdx.x; // 256
    if (b < PB_SPLIT) {
        int g = b * 256 + t;
        int o = g & 127, i = (g >> 7) & 63, c = g >> 13;
        float v = w3[(size_t)c * 8192 + i * 128 + o];
        unsigned hi = __float_as_uint(v) & 0xFFFF0000u;
        float res = v - __uint_as_float(hi);
        unsigned r2 = bf16_rne(res);
        unsigned idx = ((unsigned)c << 13) + (((o << 6) + i) ^ ((o & 7) << 3));
        B1g[idx] = (unsigned short)(hi >> 16);
        B2g[idx] = (unsigned short)r2;
    } else if (b < PB_EMLP) {
        int bb = b - PB_SPLIT;        // 0..4095
        int gi = bb >> 11;
        int e0 = (bb & 2047) * 8;
        const float* ea = gi ? ea1 : ea0;
        float* hout = gi ? h1g : h0;
        __shared__ float h1s[8][HIDD];
#pragma unroll
        for (int r = 0; r < 4; ++r) {
            int idx = r * 256 + t;
            int e1 = idx >> 7, j = idx & 127;
            float acc = b1[j];
#pragma unroll
            for (int i = 0; i < FE; ++i) acc += ea[(e0 + e1) * FE + i] * w1[i * HIDD + j];
            h1s[e1][j] = fmaxf(acc, 0.f);
        }
        __syncthreads();
#pragma unroll
        for (int r = 0; r < 2; ++r) {
            int idx = r * 256 + t;
            int e1 = idx >> 6, j = idx & 63;
            float acc = b2[j];
#pragma unroll 16
            for (int k = 0; k < HIDD; ++k) acc += h1s[e1][k] * w2[k * 64 + j];
            hout[(size_t)(e0 + e1) * 64 + j] = fmaxf(acc, 0.f);
        }
    } else if (b < PB_BIAS) {
        int bb = b - PB_EMLP;         // 0..4095
        int gi = bb >> 11;
        int n = (bb & 2047) * 2 + (t >> 7);
        int o = t & 127;
        const float* X = gi ? X1 : X0;
        float* Bb = gi ? Bb1 : Bb0;
        float acc = 0.f;
#pragma unroll 16
        for (int i = 0; i < FIN; ++i) acc += X[n * FIN + i] * b3[i * HIDD + o];
        Bb[(size_t)n * HIDD + o] = acc;
    } else {
        int tid = (b - PB_BIAS) * 256 + t; // 0..8191
        for (int idx = tid; idx < 2 * EP; idx += 32 * 256) {
            int gi = idx / EP, e = idx % EP;
            const int* dst = (gi ? ei1 : ei0) + NE;
            int d = (e < NE) ? dst[e] : e - NE;
            atomicAdd(&rowcnt[gi * NN + d], 1);
        }
    }
}

// ================= scan: rowptr per graph + batch ranges (binary search) =========
__global__ void k_scan(const int* __restrict__ rowcnt, int* __restrict__ rowptr,
                       const int* __restrict__ batch0, const int* __restrict__ batch1,
                       int* __restrict__ br) {
    int b = blockIdx.x;
    if (b < 2) {
        int gi = b;
        const int* cnt = rowcnt + gi * NN;
        int* rp = rowptr + gi * (NN + 1);
        int t = threadIdx.x; // 1024
        int base = t * 4;
        int v0 = cnt[base], v1 = cnt[base + 1], v2 = cnt[base + 2], v3 = cnt[base + 3];
        int s = v0 + v1 + v2 + v3;
        __shared__ int sc[1024];
        sc[t] = s;
        __syncthreads();
        for (int off = 1; off < 1024; off <<= 1) {
            int a = (t >= off) ? sc[t - off] : 0;
            __syncthreads();
            sc[t] += a;
            __syncthreads();
        }
        int run = sc[t] - s; // exclusive
        rp[base] = run; run += v0;
        rp[base + 1] = run; run += v1;
        rp[base + 2] = run; run += v2;
        rp[base + 3] = run; run += v3;
        if (t == 1023) rp[NN] = run;
    } else {
        int t = threadIdx.x;
        if (t < 66) {
            int gi = t / 33, g = t % 33;
            const int* batch = gi ? batch1 : batch0;
            int lo = 0, hi = NN;
            while (lo < hi) {
                int mid = (lo + hi) >> 1;
                if (batch[mid] < g) lo = mid + 1; else hi = mid;
            }
            br[gi * 33 + g] = lo;  // first index with batch >= g
        }
    }
}

// ================= fill CSR adjacency =================
__global__ void k_fill(const int* __restrict__ ei0, const int* __restrict__ ei1,
                       const int* __restrict__ rowptr, int* __restrict__ cnt2,
                       int* __restrict__ adj) {
    int idx = blockIdx.x * 256 + threadIdx.x;
    if (idx >= 2 * EP) return;
    int gi = idx / EP, e = idx % EP;
    const int* dst = (gi ? ei1 : ei0) + NE;
    int d = (e < NE) ? dst[e] : e - NE;
    int pos = rowptr[gi * (NN + 1) + d] + atomicAdd(&cnt2[gi * NN + d], 1);
    adj[gi * EP + pos] = e;
}

// ================= NNConv message GEMM -> msg[g][z][e][o] (no atomics) ========
__global__ void __launch_bounds__(256, 2)
k_nnconv(const float* __restrict__ x0, const float* __restrict__ x1,
         const float* __restrict__ h_0, const float* __restrict__ h_1,
         const unsigned short* __restrict__ B1g, const unsigned short* __restrict__ B2g,
         const float* __restrict__ Bb0, const float* __restrict__ Bb1,
         const int* __restrict__ ei0, const int* __restrict__ ei1,
         float* __restrict__ msg) {
    __shared__ __align__(16) char smem[65536]; // 2 bufs x (B1 16K | B2 16K)
    int gi = blockIdx.z;
    const float* x = gi ? x1 : x0;
    const float* hh = gi ? h_1 : h_0;
    const float* Bb = gi ? Bb1 : Bb0;
    const int* src = gi ? ei1 : ei0;

    int t = threadIdx.x;          // 256
    int e0 = blockIdx.x * 128;
    int z = blockIdx.y;           // 0..KSPLIT-1
    int wv = t >> 6, l = t & 63;
    int q4 = l >> 4, c16 = l & 15;

    // prologue: x slices + h slices for this wave's 2 row-tiles, in registers
    float xs[2][16];  // [mf][kf*8+e]: x[src[row]][kf*32 + q4*8 + e]
    float hs[2][NCH]; // [mf][cl]:     h[row][z*NCH + cl]
#pragma unroll
    for (int mf = 0; mf < 2; ++mf) {
        int r = wv * 32 + mf * 16 + c16;
        int s_ = src[e0 + r];
        const float* xr = &x[(size_t)s_ * FIN];
        *(float4*)&xs[mf][0]  = *(const float4*)&xr[q4 * 8];
        *(float4*)&xs[mf][4]  = *(const float4*)&xr[q4 * 8 + 4];
        *(float4*)&xs[mf][8]  = *(const float4*)&xr[32 + q4 * 8];
        *(float4*)&xs[mf][12] = *(const float4*)&xr[32 + q4 * 8 + 4];
        const float* hr = &hh[(size_t)(e0 + r) * 64 + z * NCH];
#pragma unroll
        for (int q = 0; q < NCH / 4; ++q)
            *(float4*)&hs[mf][q * 4] = *(const float4*)&hr[q * 4];
    }

    f4v acc[2][8];
#pragma unroll
    for (int a = 0; a < 2; ++a)
#pragma unroll
        for (int b = 0; b < 8; ++b) acc[a][b] = (f4v){0.f, 0.f, 0.f, 0.f};

    int woff = wv << 10;
#define STAGE(cg, buf)                                                         \
    {                                                                          \
        const char* b1src = (const char*)B1g + (size_t)(cg) * 16384;           \
        const char* b2src = (const char*)B2g + (size_t)(cg) * 16384;           \
        char* B1s_ = smem + (buf) * 32768;                                     \
        char* B2s_ = B1s_ + 16384;                                             \
        _Pragma("unroll")                                                      \
        for (int k2 = 0; k2 < 4; ++k2) {                                       \
            glds16(b1src + k2 * 4096 + t * 16, B1s_ + k2 * 4096 + woff);       \
            glds16(b2src + k2 * 4096 + t * 16, B2s_ + k2 * 4096 + woff);       \
        }                                                                      \
    }

    STAGE(z * NCH, 0);

#pragma unroll 1
    for (int cl = 0; cl < NCH; ++cl) {
        int buf = cl & 1;
        __builtin_amdgcn_s_barrier();          // WAR: all waves done reading buf^1
        __builtin_amdgcn_sched_barrier(0);
        if (cl + 1 < NCH) STAGE(z * NCH + cl + 1, buf ^ 1);

        // synthesize A fragments in registers (overlaps the staging loads)
        FragU a1[2][2], a2[2][2]; // [mf][kf]
#pragma unroll
        for (int mf = 0; mf < 2; ++mf) {
            float hv = hs[mf][cl];
#pragma unroll
            for (int kf = 0; kf < 2; ++kf) {
                u4v w1v, w2v;
#pragma unroll
                for (int p = 0; p < 4; ++p) {
                    float p0 = hv * xs[mf][kf * 8 + 2 * p];
                    float p1 = hv * xs[mf][kf * 8 + 2 * p + 1];
                    unsigned b0 = __float_as_uint(p0), b1 = __float_as_uint(p1);
                    unsigned hi0 = b0 & 0xFFFF0000u, hi1 = b1 & 0xFFFF0000u;
                    w1v[p] = (hi0 >> 16) | hi1;
                    float r0 = p0 - __uint_as_float(hi0);
                    float r1 = p1 - __uint_as_float(hi1);
                    w2v[p] = bf16_rne(r0) | (bf16_rne(r1) << 16);
                }
                a1[mf][kf].u = w1v; a2[mf][kf].u = w2v;
            }
        }

        if (cl + 1 < NCH) { asm volatile("s_waitcnt vmcnt(8)" ::: "memory"); }
        else             { asm volatile("s_waitcnt vmcnt(0)" ::: "memory"); }
        __builtin_amdgcn_sched_barrier(0);
        __builtin_amdgcn_s_barrier();          // buf fully staged for all waves
        __builtin_amdgcn_sched_barrier(0);

        const char* B1s = smem + buf * 32768;
        const char* B2s = B1s + 16384;
        __builtin_amdgcn_s_setprio(1);
#pragma unroll
        for (int kf = 0; kf < 2; ++kf) {
#pragma unroll
            for (int nf = 0; nf < 8; ++nf) {
                int o = nf * 16 + c16;
                int byte = o * 128 + ((kf * 64 + q4 * 16) ^ ((o & 7) << 4));
                FragU bf1, bf2;
                bf1.u = *(const u4v*)(B1s + byte);
                bf2.u = *(const u4v*)(B2s + byte);
#pragma unroll
                for (int mf = 0; mf < 2; ++mf) {
                    acc[mf][nf] = __builtin_amdgcn_mfma_f32_16x16x32_bf16(a1[mf][kf].s, bf1.s, acc[mf][nf], 0, 0, 0);
                    acc[mf][nf] = __builtin_amdgcn_mfma_f32_16x16x32_bf16(a1[mf][kf].s, bf2.s, acc[mf][nf], 0, 0, 0);
                    acc[mf][nf] = __builtin_amdgcn_mfma_f32_16x16x32_bf16(a2[mf][kf].s, bf1.s, acc[mf][nf], 0, 0, 0);
                }
            }
        }
        __builtin_amdgcn_s_setprio(0);
    }
#undef STAGE

    // epilogue: bounce acc through LDS (two 64-row halves), write coalesced float4
    float* sm = (float*)smem;  // 64 rows x 128 cols f32 = 32 KB
    float* mb = msg + ((size_t)(gi * KSPLIT + z) * NE) * HIDD;
    int z0 = (z == 0);
#pragma unroll
    for (int half = 0; half < 2; ++half) {
        __syncthreads();
        if ((wv >> 1) == half) {
            int rbase = (wv & 1) * 32;
#pragma unroll
            for (int mf = 0; mf < 2; ++mf)
#pragma unroll
                for (int j = 0; j < 4; ++j) {
                    int rr = rbase + mf * 16 + q4 * 4 + j;
#pragma unroll
                    for (int nf = 0; nf < 8; ++nf)
                        sm[rr * 128 + nf * 16 + c16] = acc[mf][nf][j];
                }
        }
        __syncthreads();
#pragma unroll
        for (int it = 0; it < 8; ++it) {
            int f = it * 256 + t;       // 0..2047 float4 index
            int row = f >> 5, c4 = f & 31;
            int eg = e0 + half * 64 + row;
            float4 v = *(float4*)&sm[row * 128 + c4 * 4];
            if (z0) {
                int s_ = src[eg];
                const float* bbr = &Bb[(size_t)s_ * HIDD + c4 * 4];
                v.x += bbr[0]; v.y += bbr[1]; v.z += bbr[2]; v.w += bbr[3];
            }
            *(float4*)&mb[(size_t)eg * HIDD + c4 * 4] = v;
        }
    }
}

// ===== h1 = relu(gather(msg) + x@root_w + cb); hp = h1@gat_w; a_s,a_d =====
__global__ void k_h1hp(const float* __restrict__ msg,
                       const int* __restrict__ rowptr, const int* __restrict__ adj,
                       const float* __restrict__ X0, const float* __restrict__ X1,
                       const float* __restrict__ rw, const float* __restrict__ cb,
                       const float* __restrict__ gw,
                       const float* __restrict__ asw, const float* __restrict__ adw,
                       float* __restrict__ hp0, float* __restrict__ hp1,
                       float* __restrict__ a_s0, float* __restrict__ a_s1,
                       float* __restrict__ a_d0, float* __restrict__ a_d1) {
    int gi = blockIdx.y;
    const float* X = gi ? X1 : X0;
    float* hp = gi ? hp1 : hp0;
    float* a_s = gi ? a_s1 : a_s0;
    float* a_d = gi ? a_d1 : a_d0;
    const int* rp = rowptr + gi * (NN + 1);
    const int* aj = adj + gi * EP;
    const float* mz0 = msg + (size_t)(gi * KSPLIT + 0) * NE * HIDD;
    const float* mz1 = msg + (size_t)(gi * KSPLIT + 1) * NE * HIDD;
    int n0 = blockIdx.x * 4;
    int o = threadIdx.x; // 128
    __shared__ float xsh[4][FIN];
    __shared__ float h1s[4][HIDD];
    __shared__ float s1[4][2], s2[4][2];
    xsh[o >> 6][o & 63] = X[n0 * FIN + o];
    xsh[2 + (o >> 6)][o & 63] = X[n0 * FIN + 128 + o];
    __syncthreads();
    float accs[4];
#pragma unroll
    for (int nn = 0; nn < 4; ++nn) {
        int n = n0 + nn;
        float acc = cb[o];
        int lo = rp[n], hi = rp[n + 1];
        for (int p = lo; p < hi; ++p) {
            int e = aj[p];
            if (e < NE) acc += mz0[(size_t)e * HIDD + o] + mz1[(size_t)e * HIDD + o];
        }
        accs[nn] = acc;
    }
#pragma unroll 8
    for (int i = 0; i < FIN; ++i) {
        float w = rw[i * HIDD + o];
#pragma unroll
        for (int nn = 0; nn < 4; ++nn) accs[nn] += xsh[nn][i] * w;
    }
#pragma unroll
    for (int nn = 0; nn < 4; ++nn) h1s[nn][o] = fmaxf(accs[nn], 0.f);
    __syncthreads();
#pragma unroll
    for (int nn = 0; nn < 4; ++nn) accs[nn] = 0.f;
#pragma unroll 8
    for (int k = 0; k < HIDD; ++k) {
        float w = gw[k * HIDD + o];
#pragma unroll
        for (int nn = 0; nn < 4; ++nn) accs[nn] += h1s[nn][k] * w;
    }
#pragma unroll
    for (int nn = 0; nn < 4; ++nn) {
        hp[(size_t)(n0 + nn) * HIDD + o] = accs[nn];
        float p1 = accs[nn] * asw[o], p2 = accs[nn] * adw[o];
#pragma unroll
        for (int off = 32; off; off >>= 1) {
            p1 += __shfl_down(p1, off);
            p2 += __shfl_down(p2, off);
        }
        if ((o & 63) == 0) { s1[nn][o >> 6] = p1; s2[nn][o >> 6] = p2; }
    }
    __syncthreads();
    if (o < 4) {
        a_s[n0 + o] = s1[o][0] + s1[o][1];
        a_d[n0 + o] = s2[o][0] + s2[o][1];
    }
}

// ===== GAT: wave per dst node; local max/denom/weighted-sum; h2 = relu(.+gb) =====
__global__ void k_gat(const int* __restrict__ rowptr, const int* __restrict__ adj,
                      const int* __restrict__ ei0, const int* __restrict__ ei1,
                      const float* __restrict__ hp0, const float* __restrict__ hp1,
                      const float* __restrict__ as0, const float* __restrict__ as1,
                      const float* __restrict__ ad0, const float* __restrict__ ad1,
                      const float* __restrict__ gb,
                      float* __restrict__ h2_0, float* __restrict__ h2_1) {
    int gi = blockIdx.y;
    const int* src = gi ? ei1 : ei0;
    const float* hp = gi ? hp1 : hp0;
    const float* a_s = gi ? as1 : as0;
    const float* a_d = gi ? ad1 : ad0;
    float* h2 = gi ? h2_1 : h2_0;
    const int* rp = rowptr + gi * (NN + 1);
    const int* aj = adj + gi * EP;
    int w = threadIdx.x >> 6, l = threadIdx.x & 63;
    int n = blockIdx.x * 4 + w;
    int lo = rp[n], deg = rp[n + 1] - lo;
    float adn = a_d[n];
    float m = -1e30f;
    for (int base = 0; base < deg; base += 64) {
        float sc = -1e30f;
        int j = base + l;
        if (j < deg) {
            int e = aj[lo + j];
            int si = (e < NE) ? src[e] : n;
            float xsc = a_s[si] + adn;
            sc = xsc > 0.f ? xsc : 0.2f * xsc;
        }
#pragma unroll
        for (int off = 32; off; off >>= 1) sc = fmaxf(sc, __shfl_xor(sc, off));
        m = fmaxf(m, sc);
    }
    float den = 0.f;
    for (int base = 0; base < deg; base += 64) {
        float ev = 0.f;
        int j = base + l;
        if (j < deg) {
            int e = aj[lo + j];
            int si = (e < NE) ? src[e] : n;
            float xsc = a_s[si] + adn;
            float sc = xsc > 0.f ? xsc : 0.2f * xsc;
            ev = expf(sc - m);
        }
#pragma unroll
        for (int off = 32; off; off >>= 1) ev += __shfl_xor(ev, off);
        den += ev;
    }
    float inv = 1.f / (den + 1e-16f);
    float acc0 = 0.f, acc1 = 0.f;
    for (int j = 0; j < deg; ++j) {
        int e = aj[lo + j];
        int si = (e < NE) ? src[e] : n;
        float xsc = a_s[si] + adn;
        float sc = xsc > 0.f ? xsc : 0.2f * xsc;
        float al = expf(sc - m) * inv;
        acc0 += al * hp[(size_t)si * HIDD + l];
        acc1 += al * hp[(size_t)si * HIDD + 64 + l];
    }
    h2[(size_t)n * HIDD + l] = fmaxf(acc0 + gb[l], 0.f);
    h2[(size_t)n * HIDD + 64 + l] = fmaxf(acc1 + gb[64 + l], 0.f);
}

// ===== mean-pool (batch ranges) + fc1, no atomics =====
__global__ void k_poolfc1(const float* __restrict__ h2_0, const float* __restrict__ h2_1,
                          const int* __restrict__ br,
                          const float* __restrict__ w, const float* __restrict__ bias,
                          float* __restrict__ z) {
    int gi = blockIdx.x >> 5, g = blockIdx.x & 31;
    const float* h2 = gi ? h2_1 : h2_0;
    int lo = br[gi * 33 + g], hi = br[gi * 33 + g + 1];
    int t = threadIdx.x; // 128
    __shared__ float pool[HIDD];
    float acc = 0.f;
    for (int n = lo; n < hi; ++n) acc += h2[(size_t)n * HIDD + t];
    pool[t] = acc;
    __syncthreads();
    if (t < 64) {
        float c = fmaxf((float)(hi - lo), 1.f);
        float a = bias[t];
#pragma unroll 16
        for (int o = 0; o < HIDD; ++o) a += (pool[o] / c) * w[o * OUTD + t];
        z[gi * NG * OUTD + g * OUTD + t] = fmaxf(a, 0.f);
    }
}

// ===== final =====
__global__ void k_final(const float* __restrict__ zz,
                        const float* __restrict__ w, const float* __restrict__ b,
                        float* __restrict__ out) {
    int g = threadIdx.x; // 32
    const float* z1 = zz;
    const float* z2 = zz + NG * OUTD;
    float acc = b[0];
#pragma unroll
    for (int j = 0; j < OUTD; ++j) acc += fabsf(z1[g * OUTD + j] - z2[g * OUTD + j]) * w[j];
    out[g] = 1.f / (1.f + expf(-acc));
}

extern "C" void kernel_launch(void* const* d_in, const int* in_sizes, int n_in,
                              void* d_out, int out_size, void* d_ws, size_t ws_size,
                              hipStream_t stream) {
    const float* x0     = (const float*)d_in[0];
    const int*   ei0    = (const int*)d_in[1];
    const float* ea0    = (const float*)d_in[2];
    const int*   b0     = (const int*)d_in[3];
    const float* x1     = (const float*)d_in[4];
    const int*   ei1    = (const int*)d_in[5];
    const float* ea1    = (const float*)d_in[6];
    const int*   b1     = (const int*)d_in[7];
    const float* e_w1 = (const float*)d_in[8];
    const float* e_b1 = (const float*)d_in[9];
    const float* e_w2 = (const float*)d_in[10];
    const float* e_b2 = (const float*)d_in[11];
    const float* e_w3 = (const float*)d_in[12];
    const float* e_b3 = (const float*)d_in[13];
    const float* root_w = (const float*)d_in[14];
    const float* conv1_b = (const float*)d_in[15];
    const float* gat_w = (const float*)d_in[16];
    const float* att_src = (const float*)d_in[17];
    const float* att_dst = (const float*)d_in[18];
    const float* gat_b = (const float*)d_in[19];
    const float* fc1_w = (const float*)d_in[20];
    const float* fc1_b = (const float*)d_in[21];
    const float* fc2_w = (const float*)d_in[22];
    const float* fc2_b = (const float*)d_in[23];

    float* ws = (float*)d_ws;
    size_t off = 0;
    auto alloc = [&](size_t n) { float* p = ws + off; off += n; return p; };
    // int region (zeroed part first)
    int* rowcnt = (int*)alloc(2 * NN);
    int* cnt2   = (int*)alloc(2 * NN);
    size_t zero_elems = off;
    int* rowptr = (int*)alloc(2 * (NN + 1));
    int* br     = (int*)alloc(66);
    int* adj    = (int*)alloc(2 * EP);
    // float scratch
    float* h[2]   = {alloc((size_t)NE * 64), alloc((size_t)NE * 64)};
    unsigned short* B1g = (unsigned short*)alloc((size_t)4096 * 128 / 2);
    unsigned short* B2g = (unsigned short*)alloc((size_t)4096 * 128 / 2);
    float* Bb[2]  = {alloc((size_t)NN * HIDD), alloc((size_t)NN * HIDD)};
    float* msg    = alloc((size_t)2 * KSPLIT * NE * HIDD);   // [g][z][e][o]
    float* hp[2]  = {alloc((size_t)NN * HIDD), alloc((size_t)NN * HIDD)};
    float* a_s[2] = {alloc(NN), alloc(NN)};
    float* a_d[2] = {alloc(NN), alloc(NN)};
    float* h2[2]  = {alloc((size_t)NN * HIDD), alloc((size_t)NN * HIDD)};
    float* zz     = alloc((size_t)2 * NG * OUTD);

    hipMemsetAsync(ws, 0, zero_elems * 4, stream);
    k_prep<<<PB_TOTAL, 256, 0, stream>>>(ea0, ea1, e_w1, e_b1, e_w2, e_b2, e_w3,
                                         x0, x1, e_b3, ei0, ei1,
                                         B1g, B2g, h[0], h[1], Bb[0], Bb[1],
                                         rowcnt);
    k_scan<<<3, 1024, 0, stream>>>(rowcnt, rowptr, b0, b1, br);
    k_fill<<<(2 * EP + 255) / 256, 256, 0, stream>>>(ei0, ei1, rowptr, cnt2, adj);
    k_nnconv<<<dim3(NE / 128, KSPLIT, 2), 256, 0, stream>>>(
        x0, x1, h[0], h[1], B1g, B2g, Bb[0], Bb[1], ei0, ei1, msg);
    k_h1hp<<<dim3(NN / 4, 2), HIDD, 0, stream>>>(
        msg, rowptr, adj, x0, x1, root_w, conv1_b, gat_w, att_src, att_dst,
        hp[0], hp[1], a_s[0], a_s[1], a_d[0], a_d[1]);
    k_gat<<<dim3(NN / 4, 2), 256, 0, stream>>>(
        rowptr, adj, ei0, ei1, hp[0], hp[1], a_s[0], a_s[1], a_d[0], a_d[1],
        gat_b, h2[0], h2[1]);
    k_poolfc1<<<64, HIDD, 0, stream>>>(h2[0], h2[1], br, fc1_w, fc1_b, zz);
    k_final<<<1, NG, 0, stream>>>(zz, fc2_w, fc2_b, (float*)d_out);
}

// Round 7
// 239.619 us; speedup vs baseline: 1.3258x; 1.0645x over previous
//
#include <hip/hip_runtime.h>
#include <hip/hip_bf16.h>
#include <math.h>

#define NN 4096      // nodes
#define NE 16384     // edges
#define FIN 64
#define FE 16
#define HIDD 128
#define OUTD 64
#define NG 32
#define EP (NE + NN) // edges + self loops
#define KSPLIT 2
#define NCH (64 / KSPLIT)  // 32 chunks per block

typedef __attribute__((ext_vector_type(4))) unsigned u4v;
typedef __attribute__((ext_vector_type(4))) float f4v;
typedef _Float16 f16x8 __attribute__((ext_vector_type(8)));
typedef __fp16 fp16x2 __attribute__((ext_vector_type(2)));

union FragH { u4v u; f16x8 h; };
union H2U { fp16x2 v; unsigned u; };

__device__ __forceinline__ void glds16(const void* g, void* l) {
    __builtin_amdgcn_global_load_lds(
        (const __attribute__((address_space(1))) unsigned*)g,
        (__attribute__((address_space(3))) unsigned*)l, 16, 0, 0);
}

// split product pair into f16 main + f16 residual (exact to ~2^-20)
__device__ __forceinline__ void split2(float p0, float p1, unsigned& w1, unsigned& w2) {
    H2U c1, c2;
    c1.v = __builtin_amdgcn_cvt_pkrtz(p0, p1);
    float r0 = p0 - (float)c1.v[0];
    float r1 = p1 - (float)c1.v[1];
    c2.v = __builtin_amdgcn_cvt_pkrtz(r0, r1);
    w1 = c1.u; w2 = c2.u;
}

// ================= prep: splitB | edge MLP | bias | dst-hist =========
#define PB_SPLIT 2048
#define PB_EMLP  (PB_SPLIT + 4096)
#define PB_BIAS  (PB_EMLP + 4096)
#define PB_TOTAL (PB_BIAS + 32)

__global__ void k_prep(const float* __restrict__ ea0, const float* __restrict__ ea1,
                       const float* __restrict__ w1, const float* __restrict__ b1,
                       const float* __restrict__ w2, const float* __restrict__ b2,
                       const float* __restrict__ w3,
                       const float* __restrict__ X0, const float* __restrict__ X1,
                       const float* __restrict__ b3,
                       const int* __restrict__ ei0, const int* __restrict__ ei1,
                       unsigned short* __restrict__ B1g,
                       float* __restrict__ h0, float* __restrict__ h1g,
                       float* __restrict__ Bb0, float* __restrict__ Bb1,
                       int* __restrict__ rowcnt) {
    int b = blockIdx.x, t = threadIdx.x; // 256
    if (b < PB_SPLIT) {
        int g = b * 256 + t;
        int o = g & 127, i = (g >> 7) & 63, c = g >> 13;
        float v = w3[(size_t)c * 8192 + i * 128 + o];
        union { _Float16 f; unsigned short u; } cv;
        cv.f = (_Float16)v;  // RNE
        unsigned idx = ((unsigned)c << 13) + (((o << 6) + i) ^ ((o & 7) << 3));
        B1g[idx] = cv.u;
    } else if (b < PB_EMLP) {
        int bb = b - PB_SPLIT;        // 0..4095
        int gi = bb >> 11;
        int e0 = (bb & 2047) * 8;
        const float* ea = gi ? ea1 : ea0;
        float* hout = gi ? h1g : h0;
        __shared__ float h1s[8][HIDD];
#pragma unroll
        for (int r = 0; r < 4; ++r) {
            int idx = r * 256 + t;
            int e1 = idx >> 7, j = idx & 127;
            float acc = b1[j];
#pragma unroll
            for (int i = 0; i < FE; ++i) acc += ea[(e0 + e1) * FE + i] * w1[i * HIDD + j];
            h1s[e1][j] = fmaxf(acc, 0.f);
        }
        __syncthreads();
#pragma unroll
        for (int r = 0; r < 2; ++r) {
            int idx = r * 256 + t;
            int e1 = idx >> 6, j = idx & 63;
            float acc = b2[j];
#pragma unroll 16
            for (int k = 0; k < HIDD; ++k) acc += h1s[e1][k] * w2[k * 64 + j];
            hout[(size_t)(e0 + e1) * 64 + j] = fmaxf(acc, 0.f);
        }
    } else if (b < PB_BIAS) {
        int bb = b - PB_EMLP;         // 0..4095
        int gi = bb >> 11;
        int n = (bb & 2047) * 2 + (t >> 7);
        int o = t & 127;
        const float* X = gi ? X1 : X0;
        float* Bb = gi ? Bb1 : Bb0;
        float acc = 0.f;
#pragma unroll 16
        for (int i = 0; i < FIN; ++i) acc += X[n * FIN + i] * b3[i * HIDD + o];
        Bb[(size_t)n * HIDD + o] = acc;
    } else {
        int tid = (b - PB_BIAS) * 256 + t; // 0..8191
        for (int idx = tid; idx < 2 * EP; idx += 32 * 256) {
            int gi = idx / EP, e = idx % EP;
            const int* dst = (gi ? ei1 : ei0) + NE;
            int d = (e < NE) ? dst[e] : e - NE;
            atomicAdd(&rowcnt[gi * NN + d], 1);
        }
    }
}

// ================= scan: rowptr per graph + batch ranges (binary search) =========
__global__ void k_scan(const int* __restrict__ rowcnt, int* __restrict__ rowptr,
                       const int* __restrict__ batch0, const int* __restrict__ batch1,
                       int* __restrict__ br) {
    int b = blockIdx.x;
    if (b < 2) {
        int gi = b;
        const int* cnt = rowcnt + gi * NN;
        int* rp = rowptr + gi * (NN + 1);
        int t = threadIdx.x; // 1024
        int base = t * 4;
        int v0 = cnt[base], v1 = cnt[base + 1], v2 = cnt[base + 2], v3 = cnt[base + 3];
        int s = v0 + v1 + v2 + v3;
        __shared__ int sc[1024];
        sc[t] = s;
        __syncthreads();
        for (int off = 1; off < 1024; off <<= 1) {
            int a = (t >= off) ? sc[t - off] : 0;
            __syncthreads();
            sc[t] += a;
            __syncthreads();
        }
        int run = sc[t] - s; // exclusive
        rp[base] = run; run += v0;
        rp[base + 1] = run; run += v1;
        rp[base + 2] = run; run += v2;
        rp[base + 3] = run; run += v3;
        if (t == 1023) rp[NN] = run;
    } else {
        int t = threadIdx.x;
        if (t < 66) {
            int gi = t / 33, g = t % 33;
            const int* batch = gi ? batch1 : batch0;
            int lo = 0, hi = NN;
            while (lo < hi) {
                int mid = (lo + hi) >> 1;
                if (batch[mid] < g) lo = mid + 1; else hi = mid;
            }
            br[gi * 33 + g] = lo;
        }
    }
}

// ================= fill CSR adjacency =================
__global__ void k_fill(const int* __restrict__ ei0, const int* __restrict__ ei1,
                       const int* __restrict__ rowptr, int* __restrict__ cnt2,
                       int* __restrict__ adj) {
    int idx = blockIdx.x * 256 + threadIdx.x;
    if (idx >= 2 * EP) return;
    int gi = idx / EP, e = idx % EP;
    const int* dst = (gi ? ei1 : ei0) + NE;
    int d = (e < NE) ? dst[e] : e - NE;
    int pos = rowptr[gi * (NN + 1) + d] + atomicAdd(&cnt2[gi * NN + d], 1);
    adj[gi * EP + pos] = e;
}

// ===== NNConv message GEMM: f16 2-product, BM=64, 2 waves, 4 blocks/CU =====
__global__ void __launch_bounds__(128, 2)
k_nnconv(const float* __restrict__ x0, const float* __restrict__ x1,
         const float* __restrict__ h_0, const float* __restrict__ h_1,
         const unsigned short* __restrict__ B1g,
         const float* __restrict__ Bb0, const float* __restrict__ Bb1,
         const int* __restrict__ ei0, const int* __restrict__ ei1,
         float* __restrict__ msg) {
    __shared__ __align__(16) char smem[32768]; // dbuf: 2 x 16KB B-chunk; reused as epilogue bounce
    int gi = blockIdx.z;
    const float* x = gi ? x1 : x0;
    const float* hh = gi ? h_1 : h_0;
    const float* Bb = gi ? Bb1 : Bb0;
    const int* src = gi ? ei1 : ei0;

    int t = threadIdx.x;          // 128
    int e0 = blockIdx.x * 64;
    int z = blockIdx.y;           // 0..KSPLIT-1
    int wv = t >> 6, l = t & 63;
    int q4 = l >> 4, c16 = l & 15;

    // prologue: x and h slices for this wave's 2 row-tiles, resident in registers
    float xs[2][16];  // [mf][kf*8+e]: x[src[row]][kf*32 + q4*8 + e]
    float hs[2][NCH]; // [mf][cl]:     h[row][z*NCH + cl]
#pragma unroll
    for (int mf = 0; mf < 2; ++mf) {
        int r = wv * 32 + mf * 16 + c16;
        int s_ = src[e0 + r];
        const float* xr = &x[(size_t)s_ * FIN];
        *(float4*)&xs[mf][0]  = *(const float4*)&xr[q4 * 8];
        *(float4*)&xs[mf][4]  = *(const float4*)&xr[q4 * 8 + 4];
        *(float4*)&xs[mf][8]  = *(const float4*)&xr[32 + q4 * 8];
        *(float4*)&xs[mf][12] = *(const float4*)&xr[32 + q4 * 8 + 4];
        const float* hr = &hh[(size_t)(e0 + r) * 64 + z * NCH];
#pragma unroll
        for (int q = 0; q < NCH / 4; ++q)
            *(float4*)&hs[mf][q * 4] = *(const float4*)&hr[q * 4];
    }

    f4v acc[2][8];
#pragma unroll
    for (int a = 0; a < 2; ++a)
#pragma unroll
        for (int b = 0; b < 8; ++b) acc[a][b] = (f4v){0.f, 0.f, 0.f, 0.f};

    // B staging: 16KB/chunk, 128 threads x 16B x 8 iters; wave-uniform LDS base + lane*16
    int woff = wv << 10; // 64 lanes * 16B
#define STAGE(cg, buf)                                                         \
    {                                                                          \
        const char* bsrc = (const char*)B1g + (size_t)(cg) * 16384;            \
        char* Bs_ = smem + (buf) * 16384;                                      \
        _Pragma("unroll")                                                      \
        for (int k2 = 0; k2 < 8; ++k2) {                                       \
            glds16(bsrc + k2 * 2048 + t * 16, Bs_ + k2 * 2048 + woff);         \
        }                                                                      \
    }

    STAGE(z * NCH, 0);

#pragma unroll 1
    for (int cl = 0; cl < NCH; ++cl) {
        int buf = cl & 1;
        __builtin_amdgcn_s_barrier();          // WAR: all waves done reading buf^1
        __builtin_amdgcn_sched_barrier(0);
        if (cl + 1 < NCH) STAGE(z * NCH + cl + 1, buf ^ 1);

        // synthesize A fragments: main + residual f16 (overlaps staging loads)
        FragH a1[2][2], a2[2][2]; // [mf][kf]
#pragma unroll
        for (int mf = 0; mf < 2; ++mf) {
            float hv = hs[mf][cl];
#pragma unroll
            for (int kf = 0; kf < 2; ++kf) {
                u4v w1v, w2v;
#pragma unroll
                for (int p = 0; p < 4; ++p) {
                    float p0 = hv * xs[mf][kf * 8 + 2 * p];
                    float p1 = hv * xs[mf][kf * 8 + 2 * p + 1];
                    unsigned u1, u2;
                    split2(p0, p1, u1, u2);
                    w1v[p] = u1; w2v[p] = u2;
                }
                a1[mf][kf].u = w1v; a2[mf][kf].u = w2v;
            }
        }

        if (cl + 1 < NCH) { asm volatile("s_waitcnt vmcnt(8)" ::: "memory"); }
        else             { asm volatile("s_waitcnt vmcnt(0)" ::: "memory"); }
        __builtin_amdgcn_sched_barrier(0);
        __builtin_amdgcn_s_barrier();          // buf fully staged for all waves
        __builtin_amdgcn_sched_barrier(0);

        const char* Bs = smem + buf * 16384;
        __builtin_amdgcn_s_setprio(1);
#pragma unroll
        for (int kf = 0; kf < 2; ++kf) {
#pragma unroll
            for (int nf = 0; nf < 8; ++nf) {
                int o = nf * 16 + c16;
                int byte = o * 128 + ((kf * 64 + q4 * 16) ^ ((o & 7) << 4));
                FragH bf;
                bf.u = *(const u4v*)(Bs + byte);
#pragma unroll
                for (int mf = 0; mf < 2; ++mf) {
                    acc[mf][nf] = __builtin_amdgcn_mfma_f32_16x16x32_f16(a1[mf][kf].h, bf.h, acc[mf][nf], 0, 0, 0);
                    acc[mf][nf] = __builtin_amdgcn_mfma_f32_16x16x32_f16(a2[mf][kf].h, bf.h, acc[mf][nf], 0, 0, 0);
                }
            }
        }
        __builtin_amdgcn_s_setprio(0);
    }
#undef STAGE

    // epilogue: bounce acc through LDS (64 rows x 128 f32 = 32KB), coalesced float4 out
    float* sm = (float*)smem;
    float* mb = msg + ((size_t)(gi * KSPLIT + z) * NE) * HIDD;
    int z0 = (z == 0);
    __builtin_amdgcn_s_barrier();
#pragma unroll
    for (int mf = 0; mf < 2; ++mf)
#pragma unroll
        for (int j = 0; j < 4; ++j) {
            int rr = wv * 32 + mf * 16 + q4 * 4 + j;
#pragma unroll
            for (int nf = 0; nf < 8; ++nf)
                sm[rr * 128 + nf * 16 + c16] = acc[mf][nf][j];
        }
    __builtin_amdgcn_s_barrier();
#pragma unroll
    for (int it = 0; it < 16; ++it) {
        int f = it * 128 + t;       // 0..2047 float4 index
        int row = f >> 5, c4 = f & 31;
        int eg = e0 + row;
        float4 v = *(float4*)&sm[row * 128 + c4 * 4];
        if (z0) {
            int s_ = src[eg];
            const float* bbr = &Bb[(size_t)s_ * HIDD + c4 * 4];
            v.x += bbr[0]; v.y += bbr[1]; v.z += bbr[2]; v.w += bbr[3];
        }
        *(float4*)&mb[(size_t)eg * HIDD + c4 * 4] = v;
    }
}

// ===== h1 = relu(gather(msg) + x@root_w + cb); hp = h1@gat_w; a_s,a_d =====
__global__ void k_h1hp(const float* __restrict__ msg,
                       const int* __restrict__ rowptr, const int* __restrict__ adj,
                       const float* __restrict__ X0, const float* __restrict__ X1,
                       const float* __restrict__ rw, const float* __restrict__ cb,
                       const float* __restrict__ gw,
                       const float* __restrict__ asw, const float* __restrict__ adw,
                       float* __restrict__ hp0, float* __restrict__ hp1,
                       float* __restrict__ a_s0, float* __restrict__ a_s1,
                       float* __restrict__ a_d0, float* __restrict__ a_d1) {
    int gi = blockIdx.y;
    const float* X = gi ? X1 : X0;
    float* hp = gi ? hp1 : hp0;
    float* a_s = gi ? a_s1 : a_s0;
    float* a_d = gi ? a_d1 : a_d0;
    const int* rp = rowptr + gi * (NN + 1);
    const int* aj = adj + gi * EP;
    const float* mz0 = msg + (size_t)(gi * KSPLIT + 0) * NE * HIDD;
    const float* mz1 = msg + (size_t)(gi * KSPLIT + 1) * NE * HIDD;
    int n0 = blockIdx.x * 4;
    int o = threadIdx.x; // 128
    __shared__ float xsh[4][FIN];
    __shared__ float h1s[4][HIDD];
    __shared__ float s1[4][2], s2[4][2];
    xsh[o >> 6][o & 63] = X[n0 * FIN + o];
    xsh[2 + (o >> 6)][o & 63] = X[n0 * FIN + 128 + o];
    __syncthreads();
    float accs[4];
#pragma unroll
    for (int nn = 0; nn < 4; ++nn) {
        int n = n0 + nn;
        float acc = cb[o];
        int lo = rp[n], hi = rp[n + 1];
        for (int p = lo; p < hi; ++p) {
            int e = aj[p];
            if (e < NE) acc += mz0[(size_t)e * HIDD + o] + mz1[(size_t)e * HIDD + o];
        }
        accs[nn] = acc;
    }
#pragma unroll 8
    for (int i = 0; i < FIN; ++i) {
        float w = rw[i * HIDD + o];
#pragma unroll
        for (int nn = 0; nn < 4; ++nn) accs[nn] += xsh[nn][i] * w;
    }
#pragma unroll
    for (int nn = 0; nn < 4; ++nn) h1s[nn][o] = fmaxf(accs[nn], 0.f);
    __syncthreads();
#pragma unroll
    for (int nn = 0; nn < 4; ++nn) accs[nn] = 0.f;
#pragma unroll 8
    for (int k = 0; k < HIDD; ++k) {
        float w = gw[k * HIDD + o];
#pragma unroll
        for (int nn = 0; nn < 4; ++nn) accs[nn] += h1s[nn][k] * w;
    }
#pragma unroll
    for (int nn = 0; nn < 4; ++nn) {
        hp[(size_t)(n0 + nn) * HIDD + o] = accs[nn];
        float p1 = accs[nn] * asw[o], p2 = accs[nn] * adw[o];
#pragma unroll
        for (int off = 32; off; off >>= 1) {
            p1 += __shfl_down(p1, off);
            p2 += __shfl_down(p2, off);
        }
        if ((o & 63) == 0) { s1[nn][o >> 6] = p1; s2[nn][o >> 6] = p2; }
    }
    __syncthreads();
    if (o < 4) {
        a_s[n0 + o] = s1[o][0] + s1[o][1];
        a_d[n0 + o] = s2[o][0] + s2[o][1];
    }
}

// ===== GAT: wave per dst node =====
__global__ void k_gat(const int* __restrict__ rowptr, const int* __restrict__ adj,
                      const int* __restrict__ ei0, const int* __restrict__ ei1,
                      const float* __restrict__ hp0, const float* __restrict__ hp1,
                      const float* __restrict__ as0, const float* __restrict__ as1,
                      const float* __restrict__ ad0, const float* __restrict__ ad1,
                      const float* __restrict__ gb,
                      float* __restrict__ h2_0, float* __restrict__ h2_1) {
    int gi = blockIdx.y;
    const int* src = gi ? ei1 : ei0;
    const float* hp = gi ? hp1 : hp0;
    const float* a_s = gi ? as1 : as0;
    const float* a_d = gi ? ad1 : ad0;
    float* h2 = gi ? h2_1 : h2_0;
    const int* rp = rowptr + gi * (NN + 1);
    const int* aj = adj + gi * EP;
    int w = threadIdx.x >> 6, l = threadIdx.x & 63;
    int n = blockIdx.x * 4 + w;
    int lo = rp[n], deg = rp[n + 1] - lo;
    float adn = a_d[n];
    float m = -1e30f;
    for (int base = 0; base < deg; base += 64) {
        float sc = -1e30f;
        int j = base + l;
        if (j < deg) {
            int e = aj[lo + j];
            int si = (e < NE) ? src[e] : n;
            float xsc = a_s[si] + adn;
            sc = xsc > 0.f ? xsc : 0.2f * xsc;
        }
#pragma unroll
        for (int off = 32; off; off >>= 1) sc = fmaxf(sc, __shfl_xor(sc, off));
        m = fmaxf(m, sc);
    }
    float den = 0.f;
    for (int base = 0; base < deg; base += 64) {
        float ev = 0.f;
        int j = base + l;
        if (j < deg) {
            int e = aj[lo + j];
            int si = (e < NE) ? src[e] : n;
            float xsc = a_s[si] + adn;
            float sc = xsc > 0.f ? xsc : 0.2f * xsc;
            ev = expf(sc - m);
        }
#pragma unroll
        for (int off = 32; off; off >>= 1) ev += __shfl_xor(ev, off);
        den += ev;
    }
    float inv = 1.f / (den + 1e-16f);
    float acc0 = 0.f, acc1 = 0.f;
    for (int j = 0; j < deg; ++j) {
        int e = aj[lo + j];
        int si = (e < NE) ? src[e] : n;
        float xsc = a_s[si] + adn;
        float sc = xsc > 0.f ? xsc : 0.2f * xsc;
        float al = expf(sc - m) * inv;
        acc0 += al * hp[(size_t)si * HIDD + l];
        acc1 += al * hp[(size_t)si * HIDD + 64 + l];
    }
    h2[(size_t)n * HIDD + l] = fmaxf(acc0 + gb[l], 0.f);
    h2[(size_t)n * HIDD + 64 + l] = fmaxf(acc1 + gb[64 + l], 0.f);
}

// ===== mean-pool (batch ranges) + fc1 =====
__global__ void k_poolfc1(const float* __restrict__ h2_0, const float* __restrict__ h2_1,
                          const int* __restrict__ br,
                          const float* __restrict__ w, const float* __restrict__ bias,
                          float* __restrict__ z) {
    int gi = blockIdx.x >> 5, g = blockIdx.x & 31;
    const float* h2 = gi ? h2_1 : h2_0;
    int lo = br[gi * 33 + g], hi = br[gi * 33 + g + 1];
    int t = threadIdx.x; // 128
    __shared__ float pool[HIDD];
    float acc = 0.f;
    for (int n = lo; n < hi; ++n) acc += h2[(size_t)n * HIDD + t];
    pool[t] = acc;
    __syncthreads();
    if (t < 64) {
        float c = fmaxf((float)(hi - lo), 1.f);
        float a = bias[t];
#pragma unroll 16
        for (int o = 0; o < HIDD; ++o) a += (pool[o] / c) * w[o * OUTD + t];
        z[gi * NG * OUTD + g * OUTD + t] = fmaxf(a, 0.f);
    }
}

// ===== final =====
__global__ void k_final(const float* __restrict__ zz,
                        const float* __restrict__ w, const float* __restrict__ b,
                        float* __restrict__ out) {
    int g = threadIdx.x; // 32
    const float* z1 = zz;
    const float* z2 = zz + NG * OUTD;
    float acc = b[0];
#pragma unroll
    for (int j = 0; j < OUTD; ++j) acc += fabsf(z1[g * OUTD + j] - z2[g * OUTD + j]) * w[j];
    out[g] = 1.f / (1.f + expf(-acc));
}

extern "C" void kernel_launch(void* const* d_in, const int* in_sizes, int n_in,
                              void* d_out, int out_size, void* d_ws, size_t ws_size,
                              hipStream_t stream) {
    const float* x0     = (const float*)d_in[0];
    const int*   ei0    = (const int*)d_in[1];
    const float* ea0    = (const float*)d_in[2];
    const int*   b0     = (const int*)d_in[3];
    const float* x1     = (const float*)d_in[4];
    const int*   ei1    = (const int*)d_in[5];
    const float* ea1    = (const float*)d_in[6];
    const int*   b1     = (const int*)d_in[7];
    const float* e_w1 = (const float*)d_in[8];
    const float* e_b1 = (const float*)d_in[9];
    const float* e_w2 = (const float*)d_in[10];
    const float* e_b2 = (const float*)d_in[11];
    const float* e_w3 = (const float*)d_in[12];
    const float* e_b3 = (const float*)d_in[13];
    const float* root_w = (const float*)d_in[14];
    const float* conv1_b = (const float*)d_in[15];
    const float* gat_w = (const float*)d_in[16];
    const float* att_src = (const float*)d_in[17];
    const float* att_dst = (const float*)d_in[18];
    const float* gat_b = (const float*)d_in[19];
    const float* fc1_w = (const float*)d_in[20];
    const float* fc1_b = (const float*)d_in[21];
    const float* fc2_w = (const float*)d_in[22];
    const float* fc2_b = (const float*)d_in[23];

    float* ws = (float*)d_ws;
    size_t off = 0;
    auto alloc = [&](size_t n) { float* p = ws + off; off += n; return p; };
    // int region (zeroed part first)
    int* rowcnt = (int*)alloc(2 * NN);
    int* cnt2   = (int*)alloc(2 * NN);
    size_t zero_elems = off;
    int* rowptr = (int*)alloc(2 * (NN + 1));
    int* br     = (int*)alloc(66);
    int* adj    = (int*)alloc(2 * EP);
    // float scratch
    float* h[2]   = {alloc((size_t)NE * 64), alloc((size_t)NE * 64)};
    unsigned short* B1g = (unsigned short*)alloc((size_t)4096 * 128 / 2); // 1MB f16 image
    float* Bb[2]  = {alloc((size_t)NN * HIDD), alloc((size_t)NN * HIDD)};
    float* msg    = alloc((size_t)2 * KSPLIT * NE * HIDD);   // [g][z][e][o]
    float* hp[2]  = {alloc((size_t)NN * HIDD), alloc((size_t)NN * HIDD)};
    float* a_s[2] = {alloc(NN), alloc(NN)};
    float* a_d[2] = {alloc(NN), alloc(NN)};
    float* h2[2]  = {alloc((size_t)NN * HIDD), alloc((size_t)NN * HIDD)};
    float* zz     = alloc((size_t)2 * NG * OUTD);

    (void)hipMemsetAsync(ws, 0, zero_elems * 4, stream);
    k_prep<<<PB_TOTAL, 256, 0, stream>>>(ea0, ea1, e_w1, e_b1, e_w2, e_b2, e_w3,
                                         x0, x1, e_b3, ei0, ei1,
                                         B1g, h[0], h[1], Bb[0], Bb[1],
                                         rowcnt);
    k_scan<<<3, 1024, 0, stream>>>(rowcnt, rowptr, b0, b1, br);
    k_fill<<<(2 * EP + 255) / 256, 256, 0, stream>>>(ei0, ei1, rowptr, cnt2, adj);
    k_nnconv<<<dim3(NE / 64, KSPLIT, 2), 128, 0, stream>>>(
        x0, x1, h[0], h[1], B1g, Bb[0], Bb[1], ei0, ei1, msg);
    k_h1hp<<<dim3(NN / 4, 2), HIDD, 0, stream>>>(
        msg, rowptr, adj, x0, x1, root_w, conv1_b, gat_w, att_src, att_dst,
        hp[0], hp[1], a_s[0], a_s[1], a_d[0], a_d[1]);
    k_gat<<<dim3(NN / 4, 2), 256, 0, stream>>>(
        rowptr, adj, ei0, ei1, hp[0], hp[1], a_s[0], a_s[1], a_d[0], a_d[1],
        gat_b, h2[0], h2[1]);
    k_poolfc1<<<64, HIDD, 0, stream>>>(h2[0], h2[1], br, fc1_w, fc1_b, zz);
    k_final<<<1, NG, 0, stream>>>(zz, fc2_w, fc2_b, (float*)d_out);
}